// Round 16
// baseline (322.447 us; speedup 1.0000x reference)
//
#include <hip/hip_runtime.h>
#include <math.h>

#define C 96
#define K 512
#define P_PER_B 110592   // 48*48*48
#define NPOS 221184      // 2 * 110592
#define MT 32            // positions per tile (2 MFMA N-sets)
#define ITERS_SIM 4
#define GRID_SIM 1728    // 1728 blocks * 4 tiles * 32 pos = 221184
#define CB 12            // 8-channel blocks (C = 96 = 12*8)

// ---------------------------------------------------------------------------
// Round 16. Round-15 post-mortem: streaming A did NOT fix the spill (WRITE
// 160MB, FETCH 310MB, sim 181us, Occ pinned 41%) -- with zero A-resident
// state the spill can only come from the SCHEDULER hoisting the 24
// independent (ah,al) pair loads of the unrolled q*t body (16 regs each)
// toward ~200 peak live. 160MB/885K threads ~ 181B/thread ~ 45 spilled regs:
// matches. The hoisting, not residency, is the cause (r13 vs r15 differ in
// what spilled, not whether).
//
// Fix: __builtin_amdgcn_sched_barrier(0) at the end of EACH t-iteration
// (24 fences) -- caps in-flight A-loads at one pair; peak live ~ acc 32 +
// B 16 + A 16 + fl 8 + addr ~20 ~ 92 <= 128. Per-wave t-steps become
// latency-exposed, which the 2-blocks/CU TLP (the point of this shape)
// covers. Everything else byte-identical to r14 (absmax=0 validated).
// Error budget unchanged: tau = 2.6e-4*||x|| + 3e-5; flagged (~1%)
// re-resolved bit-exactly by refine (v2, unchanged).
// ---------------------------------------------------------------------------

typedef _Float16 f16;
typedef _Float16 f16x8 __attribute__((ext_vector_type(8)));
typedef float f32x4 __attribute__((ext_vector_type(4)));

// Workspace: pnT[96][512] fp32 numpy-exact (192KB, refine) +
// pn16h/pn16l fragment-linear f16 (96KB each). Total 384KB.

__device__ __forceinline__ size_t fidx(int k, int c) {
    // [kt][q][lg][l15][j]: kt=k>>4, q=c>>5, lg=(c>>3)&3, l15=k&15, j=c&7
    return (size_t)(((((k >> 4) * 3 + (c >> 5)) * 4 + ((c >> 3) & 3)) * 16
                     + (k & 15)) * 8 + (c & 7));
}

__global__ __launch_bounds__(256) void prep_kernel(const float* __restrict__ proto,
                                                   float* __restrict__ pnT,
                                                   f16* __restrict__ pn16h,
                                                   f16* __restrict__ pn16l) {
    int k = blockIdx.x * 256 + threadIdx.x;
    if (k >= K) return;
    const float* row = proto + k * C;
    // numpy pairwise_sum, n=96 <= blocksize: 8 accumulators + fixed combine
    float r[8];
#pragma unroll
    for (int j = 0; j < 8; ++j) r[j] = __fmul_rn(row[j], row[j]);
    for (int i = 8; i < C; i += 8) {
#pragma unroll
        for (int j = 0; j < 8; ++j)
            r[j] = __fadd_rn(r[j], __fmul_rn(row[i + j], row[i + j]));
    }
    float res = __fadd_rn(__fadd_rn(__fadd_rn(r[0], r[1]), __fadd_rn(r[2], r[3])),
                          __fadd_rn(__fadd_rn(r[4], r[5]), __fadd_rn(r[6], r[7])));
    float n = fmaxf(__fsqrt_rn(res), 1e-12f);
    for (int c = 0; c < C; ++c) {
        float v = __fdiv_rn(row[c], n);
        pnT[(size_t)c * K + k] = v;            // exact fp32, channel-major (refine)
        f16 h = (f16)v;                        // RTNE hi
        size_t fi = fidx(k, c);
        pn16h[fi] = h;
        pn16l[fi] = (f16)(v - (float)h);       // exact residual -> RTNE lo
    }
}

// ---------------------------------------------------------------------------
// Fast pass: compensated f16 MFMA argmax. 512 threads = 8 waves; wave w owns
// protos [w*64, w*64+64) as 4 M-tiles (kt = 4w+t); 32 positions as 2 N-sets.
// A (both planes) streamed per (q,t) as coalesced 1KB L2 reads, with a
// sched_barrier(0) per t-iteration to stop load-hoisting (the r13/r15 spill).
// ---------------------------------------------------------------------------
__global__ __launch_bounds__(512, 4) void sim_argmax_kernel(
        const float* __restrict__ x,
        const f16* __restrict__ pn16h,
        const f16* __restrict__ pn16l,
        int* __restrict__ out) {
    __shared__ __align__(16) f16 xth[CB * MT * 8];   // [cb][pos][8] hi, 6 KB
    __shared__ __align__(16) f16 xtl[CB * MT * 8];   // lo plane,     6 KB
    __shared__ float n2p[CB][MT];                    // ||x||^2 partials
    __shared__ float wm1[8][MT], wm2[8][MT];         // per-wave top-2

    const int tid = threadIdx.x;
    const int lane = tid & 63;
    const int w = tid >> 6;          // wave 0..7
    const int l15 = lane & 15;
    const int lg = lane >> 4;        // 0..3 (k-group)

    // per-lane A-fragment byte base: frag (kt,q) at ((kt*3+q)*4+lg)*128+l15*8
    const int abase = lg * 128 + l15 * 8;

    // staging role: waves 0..5, half-wave = channel block, lane&31 = pos
    const int cb = (w << 1) + (lane >> 5);           // 0..11 for w<6
    const int ps = lane & 31;
    const int m00 = blockIdx.x * (MT * ITERS_SIM);   // 110592 % 128 == 0:
    const int b = (m00 >= P_PER_B) ? 1 : 0;          // no batch straddle
    const float* xq = x + (size_t)b * (size_t)C * P_PER_B + (m00 - b * P_PER_B)
                    + (size_t)(cb << 3) * P_PER_B + ps;   // deref only if w < 6

    // prologue: tile 0's x into registers (T14)
    float fl[8];
    if (w < 6) {
#pragma unroll
        for (int j = 0; j < 8; ++j) fl[j] = xq[(size_t)j * P_PER_B];
    }

#pragma unroll 1
    for (int it = 0; it < ITERS_SIM; ++it) {
        const int m0 = m00 + it * MT;

        __syncthreads();   // prev iter's xt/n2p/wm readers done

        // ---- stage: 8 ch/thread, one b128 store per plane ----
        if (w < 6) {
            float ss = 0.f;
            f16x8 vh, vl;
#pragma unroll
            for (int j = 0; j < 8; ++j) {
                float v = fl[j];
                ss = fmaf(v, v, ss);
                f16 h = (f16)v;                   // RTNE hi
                vh[j] = h;
                vl[j] = (f16)(v - (float)h);      // exact residual
            }
            n2p[cb][ps] = ss;
            *(f16x8*)(xth + ((cb * MT + ps) << 3)) = vh;
            *(f16x8*)(xtl + ((cb * MT + ps) << 3)) = vl;
        }
        __syncthreads();

        // ---- T14: issue next tile's loads now; consumed next iter ----
        if (w < 6 && it + 1 < ITERS_SIM) {
#pragma unroll
            for (int j = 0; j < 8; ++j)
                fl[j] = xq[(size_t)j * P_PER_B + (it + 1) * MT];
        }

        // ---- MFMA: D[proto][pos] = hh + lh + hl; A streamed per (q,t),
        //      sched_barrier(0) per t caps in-flight loads (anti-spill) ----
        f32x4 acc[2][4];
#pragma unroll
        for (int s = 0; s < 2; ++s)
#pragma unroll
            for (int t = 0; t < 4; ++t)
                acc[s][t] = (f32x4){0.f, 0.f, 0.f, 0.f};

        __builtin_amdgcn_s_setprio(1);
#pragma unroll
        for (int q = 0; q < 3; ++q) {
            const int cbase = ((q * 4 + lg) * MT) << 3;   // channel-block base
            f16x8 b0h = *(const f16x8*)(xth + cbase + (l15 << 3));
            f16x8 b1h = *(const f16x8*)(xth + cbase + ((16 + l15) << 3));
            f16x8 b0l = *(const f16x8*)(xtl + cbase + (l15 << 3));
            f16x8 b1l = *(const f16x8*)(xtl + cbase + ((16 + l15) << 3));
#pragma unroll
            for (int t = 0; t < 4; ++t) {
                const size_t fb = (size_t)(((4 * w + t) * 3 + q) * 512) + abase;
                f16x8 ah = *(const f16x8*)(pn16h + fb);
                f16x8 al = *(const f16x8*)(pn16l + fb);
                acc[0][t] = __builtin_amdgcn_mfma_f32_16x16x32_f16(ah, b0h, acc[0][t], 0, 0, 0);
                acc[1][t] = __builtin_amdgcn_mfma_f32_16x16x32_f16(ah, b1h, acc[1][t], 0, 0, 0);
                acc[0][t] = __builtin_amdgcn_mfma_f32_16x16x32_f16(al, b0h, acc[0][t], 0, 0, 0);
                acc[1][t] = __builtin_amdgcn_mfma_f32_16x16x32_f16(al, b1h, acc[1][t], 0, 0, 0);
                acc[0][t] = __builtin_amdgcn_mfma_f32_16x16x32_f16(ah, b0l, acc[0][t], 0, 0, 0);
                acc[1][t] = __builtin_amdgcn_mfma_f32_16x16x32_f16(ah, b1l, acc[1][t], 0, 0, 0);
                __builtin_amdgcn_sched_barrier(0);   // cap live A-loads at 1 pair
            }
        }
        __builtin_amdgcn_s_setprio(0);

        // ---- branchless packed top-2 (k in low 9 mantissa bits) ----
        float m1[2], m2[2];
        m1[0] = m1[1] = -3.4e38f;
        m2[0] = m2[1] = -3.4e38f;
        const int kb = w * 64 + (lg << 2);
#pragma unroll
        for (int t = 0; t < 4; ++t)
#pragma unroll
            for (int r = 0; r < 4; ++r) {
                const int kk = kb + t * 16 + r;   // folds to and_or + add
#pragma unroll
                for (int s = 0; s < 2; ++s) {
                    float v = acc[s][t][r];
                    float pk = __uint_as_float(
                        (__float_as_uint(v) & 0xFFFFFE00u) | (unsigned)kk);
                    m2[s] = fmaxf(m2[s], fminf(m1[s], pk));
                    m1[s] = fmaxf(m1[s], pk);
                }
            }

        // ---- merge the 4 k-groups sharing a position (masks 16, 32) ----
#pragma unroll
        for (int m = 16; m <= 32; m <<= 1)
#pragma unroll
            for (int s = 0; s < 2; ++s) {
                float o1 = __shfl_xor(m1[s], m);
                float o2 = __shfl_xor(m2[s], m);
                m2[s] = fmaxf(fmaxf(m2[s], o2), fminf(m1[s], o1));
                m1[s] = fmaxf(m1[s], o1);
            }
        if (lane < 16) {
            wm1[w][l15] = m1[0];      wm2[w][l15] = m2[0];
            wm1[w][16 + l15] = m1[1]; wm2[w][16 + l15] = m2[1];
        }
        __syncthreads();

        // ---- final merge across 8 waves (disjoint proto sets) + tau ----
        if (tid < MT) {
            float n2 = 0.f;
#pragma unroll
            for (int g = 0; g < CB; ++g) n2 += n2p[g][tid];
            float b_ = wm1[0][tid], s_ = wm2[0][tid];
#pragma unroll
            for (int ww = 1; ww < 8; ++ww) {
                float o1 = wm1[ww][tid], o2 = wm2[ww][tid];
                s_ = fmaxf(fmaxf(s_, o2), fminf(b_, o1));
                b_ = fmaxf(b_, o1);
            }
            // tau >= 2*(pack 6.1e-5 + fast 2.2e-5 + numpy 1.8e-5) = 2.02e-4
            float tau = 2.6e-4f * sqrtf(n2) + 3e-5f;
            int k_ = (int)(__float_as_uint(b_) & 511u);
            out[m0 + tid] = (b_ - s_ < tau) ? (k_ | (int)0x80000000) : k_;
        }
    }
}

// ---------------------------------------------------------------------------
// Refine pass (byte-identical to r11/r12, validated): bit-exact numpy-fp32
// emulation of flagged positions; 4-wave-parallel; 32-pos segments.
// ---------------------------------------------------------------------------
__global__ __launch_bounds__(256) void refine_kernel(
        const float* __restrict__ x,
        const float* __restrict__ pnT,
        int* __restrict__ out) {
    __shared__ int list[32];
    __shared__ int cnt;
    __shared__ float xn4[4][C];
    __shared__ float nrm4[4];

    const int tid = threadIdx.x;
    const int lane = tid & 63;
    const int w = tid >> 6;          // wave 0..3

    if (tid == 0) cnt = 0;
    __syncthreads();

    if (tid < 32) {
        int g = blockIdx.x * 32 + tid;
        if (out[g] < 0) {
            int i = atomicAdd(&cnt, 1);
            list[i] = g;
        }
    }
    __syncthreads();
    const int n = cnt;
    const int nmax = (n + 3) >> 2;

    for (int j = 0; j < nmax; ++j) {
        const int idx = j * 4 + w;
        const bool act = idx < n;
        const int gg = act ? list[idx] : list[0];
        const int b = (gg >= P_PER_B) ? 1 : 0;
        const int p = gg - b * P_PER_B;
        const float* xb = x + (size_t)b * (size_t)C * P_PER_B + p;

        if (act) {
            xn4[w][lane] = xb[(size_t)lane * P_PER_B];
            if (lane < C - 64) xn4[w][64 + lane] = xb[(size_t)(64 + lane) * P_PER_B];
        }
        __syncthreads();

        // numpy: norm over non-contiguous axis -> strictly sequential fp32
        if (act && lane == 0) {
            float a = __fmul_rn(xn4[w][0], xn4[w][0]);
            for (int c = 1; c < C; ++c)
                a = __fadd_rn(a, __fmul_rn(xn4[w][c], xn4[w][c]));
            nrm4[w] = fmaxf(__fsqrt_rn(a), 1e-12f);
        }
        __syncthreads();
        if (act) {
            xn4[w][lane] = __fdiv_rn(xn4[w][lane], nrm4[w]);
            if (lane < C - 64)
                xn4[w][64 + lane] = __fdiv_rn(xn4[w][64 + lane], nrm4[w]);
        }
        __syncthreads();

        if (act) {
            // einsum optimize=False: sequential fp32 mul+add, c ascending,
            // no FMA. Lane handles protos lane + 64*r, r = 0..7.
            float s[8];
#pragma unroll
            for (int r = 0; r < 8; ++r) s[r] = 0.f;
            for (int c = 0; c < C; ++c) {
                float xc = xn4[w][c];
                const float* pr = pnT + (size_t)c * K + lane;
#pragma unroll
                for (int r = 0; r < 8; ++r)
                    s[r] = __fadd_rn(s[r], __fmul_rn(xc, pr[r * 64]));
            }
            // per-lane best over r (k ascending: strict > keeps lowest k)
            float bv = s[0];
            int bk = lane;
#pragma unroll
            for (int r = 1; r < 8; ++r) {
                if (s[r] > bv) { bv = s[r]; bk = lane + r * 64; }
            }
            // wave-level argmax (exact compares, min-index tie-break)
#pragma unroll
            for (int off = 1; off < 64; off <<= 1) {
                float ov = __shfl_xor(bv, off);
                int oi = __shfl_xor(bk, off);
                if (ov > bv || (ov == bv && oi < bk)) { bv = ov; bk = oi; }
            }
            if (lane == 0) out[gg] = bk;
        }
    }
}

// ---------------------------------------------------------------------------
extern "C" void kernel_launch(void* const* d_in, const int* in_sizes, int n_in,
                              void* d_out, int out_size, void* d_ws, size_t ws_size,
                              hipStream_t stream) {
    const float* x = (const float*)d_in[0];      // [2,96,48,48,48] fp32
    const float* proto = (const float*)d_in[1];  // [512,96] fp32
    int* out = (int*)d_out;                      // [2,48,48,48] int32

    float* pnT = (float*)d_ws;                        // 96*512*4  = 196608 B
    f16* pn16h = (f16*)((char*)d_ws + 196608);        // 512*96*2  =  98304 B
    f16* pn16l = (f16*)((char*)d_ws + 294912);        // 512*96*2  =  98304 B

    prep_kernel<<<2, 256, 0, stream>>>(proto, pnT, pn16h, pn16l);
    sim_argmax_kernel<<<GRID_SIM, 512, 0, stream>>>(x, pn16h, pn16l, out);
    refine_kernel<<<NPOS / 32, 256, 0, stream>>>(x, pnT, out);
}

// Round 18
// 228.077 us; speedup vs baseline: 1.4138x; 1.4138x over previous
//
#include <hip/hip_runtime.h>
#include <math.h>

#define C 96
#define K 512
#define P_PER_B 110592   // 48*48*48
#define NPOS 221184      // 2 * 110592
#define MT 32            // positions per tile (2 MFMA N-sets)
#define ITERS_SIM 2
#define GRID_SIM 3456    // 3456 blocks * 2 tiles * 32 pos = 221184
#define CB 12            // 8-channel blocks (C = 96 = 12*8)

// ---------------------------------------------------------------------------
// Round 18 (r17 resubmit + audit fix; r17 broker timeout). AUDIT FIX: r17's
// kb = w*128 + kt0*16 double-counted the wave offset (kt0 = 8w+2ktp already
// includes it) -> packed kk up to 895 overflowed the 9-bit field for w>=1.
// Now kb = kt0*16 + (lg<<2).
//
// Context: 512-thr launch_bounds(512,4) spilled identically 3x (WRITE
// exactly 159840KB, r13/r15/r16) regardless of inner-loop shape ->
// structural 64+64 unified-file split; abandoned. r12 (1024-thr, 108.6us,
// no spill) capped by ONE block/CU lockstep phases (~4K of 19K cyc/iter).
//
// This shape: 256-thr/4-wave blocks, minimal state -> real cross-block TLP.
//  - wave owns 128 protos as 4 sequential kt-PAIRS; per-pair acc (16 AGPR)
//    folded into packed top-2 after each pair.
//  - B-hi resident (24 regs); B-lo streamed from LDS per q; BOTH A planes
//    streamed as coalesced 1KB L2 reads (fragment-linear, validated).
//  - arch ~90 <= 128 (launch_bounds(256,4), no spill) -> ~5 blocks/CU:
//    stage/merge of one block overlaps other blocks' MFMAs.
// Error budget unchanged (absmax=0 validated 5x): tau = 2.6e-4*||x|| + 3e-5;
// flagged (~1%) re-resolved bit-exactly by refine (v2, unchanged).
// ---------------------------------------------------------------------------

typedef _Float16 f16;
typedef _Float16 f16x8 __attribute__((ext_vector_type(8)));
typedef float f32x4 __attribute__((ext_vector_type(4)));

// Workspace: pnT[96][512] fp32 numpy-exact (192KB, refine) +
// pn16h/pn16l fragment-linear f16 (96KB each). Total 384KB.

__device__ __forceinline__ size_t fidx(int k, int c) {
    // [kt][q][lg][l15][j]: kt=k>>4, q=c>>5, lg=(c>>3)&3, l15=k&15, j=c&7
    return (size_t)(((((k >> 4) * 3 + (c >> 5)) * 4 + ((c >> 3) & 3)) * 16
                     + (k & 15)) * 8 + (c & 7));
}

__global__ __launch_bounds__(256) void prep_kernel(const float* __restrict__ proto,
                                                   float* __restrict__ pnT,
                                                   f16* __restrict__ pn16h,
                                                   f16* __restrict__ pn16l) {
    int k = blockIdx.x * 256 + threadIdx.x;
    if (k >= K) return;
    const float* row = proto + k * C;
    // numpy pairwise_sum, n=96 <= blocksize: 8 accumulators + fixed combine
    float r[8];
#pragma unroll
    for (int j = 0; j < 8; ++j) r[j] = __fmul_rn(row[j], row[j]);
    for (int i = 8; i < C; i += 8) {
#pragma unroll
        for (int j = 0; j < 8; ++j)
            r[j] = __fadd_rn(r[j], __fmul_rn(row[i + j], row[i + j]));
    }
    float res = __fadd_rn(__fadd_rn(__fadd_rn(r[0], r[1]), __fadd_rn(r[2], r[3])),
                          __fadd_rn(__fadd_rn(r[4], r[5]), __fadd_rn(r[6], r[7])));
    float n = fmaxf(__fsqrt_rn(res), 1e-12f);
    for (int c = 0; c < C; ++c) {
        float v = __fdiv_rn(row[c], n);
        pnT[(size_t)c * K + k] = v;            // exact fp32, channel-major (refine)
        f16 h = (f16)v;                        // RTNE hi
        size_t fi = fidx(k, c);
        pn16h[fi] = h;
        pn16l[fi] = (f16)(v - (float)h);       // exact residual -> RTNE lo
    }
}

// ---------------------------------------------------------------------------
// Fast pass: compensated f16 MFMA argmax. 256 threads = 4 waves; wave w owns
// protos [w*128, w*128+128) as 4 kt-PAIRS processed sequentially; 32
// positions as 2 N-sets. Per pair: 3q x 12 = 36 MFMAs -> fold into top-2.
// ---------------------------------------------------------------------------
__global__ __launch_bounds__(256, 4) void sim_argmax_kernel(
        const float* __restrict__ x,
        const f16* __restrict__ pn16h,
        const f16* __restrict__ pn16l,
        int* __restrict__ out) {
    __shared__ __align__(16) f16 xth[CB * MT * 8];   // [cb][pos][8] hi, 6 KB
    __shared__ __align__(16) f16 xtl[CB * MT * 8];   // lo plane,     6 KB
    __shared__ float n2p[CB][MT];                    // ||x||^2 partials
    __shared__ float wm1[4][MT], wm2[4][MT];         // per-wave top-2

    const int tid = threadIdx.x;
    const int lane = tid & 63;
    const int w = tid >> 6;          // wave 0..3
    const int l15 = lane & 15;
    const int lg = lane >> 4;        // 0..3 (k-group)

    const int m00 = blockIdx.x * (MT * ITERS_SIM);   // 110592 % 64 == 0:
    const int b = (m00 >= P_PER_B) ? 1 : 0;          // no batch straddle
    const float* xb = x + (size_t)b * (size_t)C * P_PER_B + (m00 - b * P_PER_B);

#pragma unroll 1
    for (int it = 0; it < ITERS_SIM; ++it) {
        const int m0 = m00 + it * MT;

        __syncthreads();   // prev iter's xt/n2p/wm readers done

        // ---- stage: 384 slots (cb,pos) over 256 threads; 8 ch each ----
        for (int sl = tid; sl < CB * MT; sl += 256) {
            const int scb = sl >> 5, sps = sl & 31;
            const float* xp = xb + (size_t)(scb << 3) * P_PER_B + it * MT + sps;
            float ss = 0.f;
            f16x8 vh, vl;
#pragma unroll
            for (int j = 0; j < 8; ++j) {
                float v = xp[(size_t)j * P_PER_B];
                ss = fmaf(v, v, ss);
                f16 h = (f16)v;                   // RTNE hi
                vh[j] = h;
                vl[j] = (f16)(v - (float)h);      // exact residual
            }
            n2p[scb][sps] = ss;
            *(f16x8*)(xth + (sl << 3)) = vh;
            *(f16x8*)(xtl + (sl << 3)) = vl;
        }
        __syncthreads();

        // ---- B-hi resident for this tile (24 VGPR) ----
        f16x8 bh[2][3];
#pragma unroll
        for (int s = 0; s < 2; ++s)
#pragma unroll
            for (int q = 0; q < 3; ++q)
                bh[s][q] = *(const f16x8*)(xth
                    + (((q * 4 + lg) * MT + s * 16 + l15) << 3));

        // ---- kt-pair loop: MFMA + immediate top-2 fold ----
        float m1[2], m2[2];
        m1[0] = m1[1] = -3.4e38f;
        m2[0] = m2[1] = -3.4e38f;

        __builtin_amdgcn_s_setprio(1);
#pragma unroll 1
        for (int ktp = 0; ktp < 4; ++ktp) {
            const int kt0 = 8 * w + 2 * ktp;
            f32x4 acc[2][2];   // [i: kt in pair][s]
#pragma unroll
            for (int i = 0; i < 2; ++i)
#pragma unroll
                for (int s = 0; s < 2; ++s)
                    acc[i][s] = (f32x4){0.f, 0.f, 0.f, 0.f};
#pragma unroll
            for (int q = 0; q < 3; ++q) {
                const size_t fb0 = (size_t)(((kt0 * 3 + q) * 4 + lg) * 128)
                                 + l15 * 8;
                const size_t fb1 = fb0 + 1536;   // (kt0+1): +3*4*128
                f16x8 ah0 = *(const f16x8*)(pn16h + fb0);
                f16x8 ah1 = *(const f16x8*)(pn16h + fb1);
                f16x8 al0 = *(const f16x8*)(pn16l + fb0);
                f16x8 al1 = *(const f16x8*)(pn16l + fb1);
                f16x8 bl0 = *(const f16x8*)(xtl + (((q * 4 + lg) * MT + l15) << 3));
                f16x8 bl1 = *(const f16x8*)(xtl + (((q * 4 + lg) * MT + 16 + l15) << 3));
                acc[0][0] = __builtin_amdgcn_mfma_f32_16x16x32_f16(ah0, bh[0][q], acc[0][0], 0, 0, 0);
                acc[0][1] = __builtin_amdgcn_mfma_f32_16x16x32_f16(ah0, bh[1][q], acc[0][1], 0, 0, 0);
                acc[1][0] = __builtin_amdgcn_mfma_f32_16x16x32_f16(ah1, bh[0][q], acc[1][0], 0, 0, 0);
                acc[1][1] = __builtin_amdgcn_mfma_f32_16x16x32_f16(ah1, bh[1][q], acc[1][1], 0, 0, 0);
                acc[0][0] = __builtin_amdgcn_mfma_f32_16x16x32_f16(al0, bh[0][q], acc[0][0], 0, 0, 0);
                acc[0][1] = __builtin_amdgcn_mfma_f32_16x16x32_f16(al0, bh[1][q], acc[0][1], 0, 0, 0);
                acc[1][0] = __builtin_amdgcn_mfma_f32_16x16x32_f16(al1, bh[0][q], acc[1][0], 0, 0, 0);
                acc[1][1] = __builtin_amdgcn_mfma_f32_16x16x32_f16(al1, bh[1][q], acc[1][1], 0, 0, 0);
                acc[0][0] = __builtin_amdgcn_mfma_f32_16x16x32_f16(ah0, bl0, acc[0][0], 0, 0, 0);
                acc[0][1] = __builtin_amdgcn_mfma_f32_16x16x32_f16(ah0, bl1, acc[0][1], 0, 0, 0);
                acc[1][0] = __builtin_amdgcn_mfma_f32_16x16x32_f16(ah1, bl0, acc[1][0], 0, 0, 0);
                acc[1][1] = __builtin_amdgcn_mfma_f32_16x16x32_f16(ah1, bl1, acc[1][1], 0, 0, 0);
            }
            // fold pair into packed top-2 (k in low 9 mantissa bits).
            // kt0 already includes the wave offset (kt0 = 8w+2ktp) -> proto
            // index = kt0*16 + i*16 + lg*4 + r.  [r18 audit fix]
            const int kb = kt0 * 16 + (lg << 2);
#pragma unroll
            for (int i = 0; i < 2; ++i)
#pragma unroll
                for (int r = 0; r < 4; ++r) {
                    const int kk = kb + i * 16 + r;
#pragma unroll
                    for (int s = 0; s < 2; ++s) {
                        float v = acc[i][s][r];
                        float pk = __uint_as_float(
                            (__float_as_uint(v) & 0xFFFFFE00u) | (unsigned)kk);
                        m2[s] = fmaxf(m2[s], fminf(m1[s], pk));
                        m1[s] = fmaxf(m1[s], pk);
                    }
                }
        }
        __builtin_amdgcn_s_setprio(0);

        // ---- merge the 4 k-groups sharing a position (masks 16, 32) ----
#pragma unroll
        for (int m = 16; m <= 32; m <<= 1)
#pragma unroll
            for (int s = 0; s < 2; ++s) {
                float o1 = __shfl_xor(m1[s], m);
                float o2 = __shfl_xor(m2[s], m);
                m2[s] = fmaxf(fmaxf(m2[s], o2), fminf(m1[s], o1));
                m1[s] = fmaxf(m1[s], o1);
            }
        if (lane < 16) {
            wm1[w][l15] = m1[0];      wm2[w][l15] = m2[0];
            wm1[w][16 + l15] = m1[1]; wm2[w][16 + l15] = m2[1];
        }
        __syncthreads();

        // ---- final merge across 4 waves (disjoint proto sets) + tau ----
        if (tid < MT) {
            float n2 = 0.f;
#pragma unroll
            for (int g = 0; g < CB; ++g) n2 += n2p[g][tid];
            float b_ = wm1[0][tid], s_ = wm2[0][tid];
#pragma unroll
            for (int ww = 1; ww < 4; ++ww) {
                float o1 = wm1[ww][tid], o2 = wm2[ww][tid];
                s_ = fmaxf(fmaxf(s_, o2), fminf(b_, o1));
                b_ = fmaxf(b_, o1);
            }
            // tau >= 2*(pack 6.1e-5 + fast 2.2e-5 + numpy 1.8e-5) = 2.02e-4
            float tau = 2.6e-4f * sqrtf(n2) + 3e-5f;
            int k_ = (int)(__float_as_uint(b_) & 511u);
            out[m0 + tid] = (b_ - s_ < tau) ? (k_ | (int)0x80000000) : k_;
        }
    }
}

// ---------------------------------------------------------------------------
// Refine pass (byte-identical to r11/r12, validated): bit-exact numpy-fp32
// emulation of flagged positions; 4-wave-parallel; 32-pos segments.
// ---------------------------------------------------------------------------
__global__ __launch_bounds__(256) void refine_kernel(
        const float* __restrict__ x,
        const float* __restrict__ pnT,
        int* __restrict__ out) {
    __shared__ int list[32];
    __shared__ int cnt;
    __shared__ float xn4[4][C];
    __shared__ float nrm4[4];

    const int tid = threadIdx.x;
    const int lane = tid & 63;
    const int w = tid >> 6;          // wave 0..3

    if (tid == 0) cnt = 0;
    __syncthreads();

    if (tid < 32) {
        int g = blockIdx.x * 32 + tid;
        if (out[g] < 0) {
            int i = atomicAdd(&cnt, 1);
            list[i] = g;
        }
    }
    __syncthreads();
    const int n = cnt;
    const int nmax = (n + 3) >> 2;

    for (int j = 0; j < nmax; ++j) {
        const int idx = j * 4 + w;
        const bool act = idx < n;
        const int gg = act ? list[idx] : list[0];
        const int b = (gg >= P_PER_B) ? 1 : 0;
        const int p = gg - b * P_PER_B;
        const float* xb = x + (size_t)b * (size_t)C * P_PER_B + p;

        if (act) {
            xn4[w][lane] = xb[(size_t)lane * P_PER_B];
            if (lane < C - 64) xn4[w][64 + lane] = xb[(size_t)(64 + lane) * P_PER_B];
        }
        __syncthreads();

        // numpy: norm over non-contiguous axis -> strictly sequential fp32
        if (act && lane == 0) {
            float a = __fmul_rn(xn4[w][0], xn4[w][0]);
            for (int c = 1; c < C; ++c)
                a = __fadd_rn(a, __fmul_rn(xn4[w][c], xn4[w][c]));
            nrm4[w] = fmaxf(__fsqrt_rn(a), 1e-12f);
        }
        __syncthreads();
        if (act) {
            xn4[w][lane] = __fdiv_rn(xn4[w][lane], nrm4[w]);
            if (lane < C - 64)
                xn4[w][64 + lane] = __fdiv_rn(xn4[w][64 + lane], nrm4[w]);
        }
        __syncthreads();

        if (act) {
            // einsum optimize=False: sequential fp32 mul+add, c ascending,
            // no FMA. Lane handles protos lane + 64*r, r = 0..7.
            float s[8];
#pragma unroll
            for (int r = 0; r < 8; ++r) s[r] = 0.f;
            for (int c = 0; c < C; ++c) {
                float xc = xn4[w][c];
                const float* pr = pnT + (size_t)c * K + lane;
#pragma unroll
                for (int r = 0; r < 8; ++r)
                    s[r] = __fadd_rn(s[r], __fmul_rn(xc, pr[r * 64]));
            }
            // per-lane best over r (k ascending: strict > keeps lowest k)
            float bv = s[0];
            int bk = lane;
#pragma unroll
            for (int r = 1; r < 8; ++r) {
                if (s[r] > bv) { bv = s[r]; bk = lane + r * 64; }
            }
            // wave-level argmax (exact compares, min-index tie-break)
#pragma unroll
            for (int off = 1; off < 64; off <<= 1) {
                float ov = __shfl_xor(bv, off);
                int oi = __shfl_xor(bk, off);
                if (ov > bv || (ov == bv && oi < bk)) { bv = ov; bk = oi; }
            }
            if (lane == 0) out[gg] = bk;
        }
    }
}

// ---------------------------------------------------------------------------
extern "C" void kernel_launch(void* const* d_in, const int* in_sizes, int n_in,
                              void* d_out, int out_size, void* d_ws, size_t ws_size,
                              hipStream_t stream) {
    const float* x = (const float*)d_in[0];      // [2,96,48,48,48] fp32
    const float* proto = (const float*)d_in[1];  // [512,96] fp32
    int* out = (int*)d_out;                      // [2,48,48,48] int32

    float* pnT = (float*)d_ws;                        // 96*512*4  = 196608 B
    f16* pn16h = (f16*)((char*)d_ws + 196608);        // 512*96*2  =  98304 B
    f16* pn16l = (f16*)((char*)d_ws + 294912);        // 512*96*2  =  98304 B

    prep_kernel<<<2, 256, 0, stream>>>(proto, pnT, pn16h, pn16l);
    sim_argmax_kernel<<<GRID_SIM, 256, 0, stream>>>(x, pn16h, pn16l, out);
    refine_kernel<<<NPOS / 32, 256, 0, stream>>>(x, pnT, out);
}